// Round 5
// baseline (438.377 us; speedup 1.0000x reference)
//
#include <hip/hip_runtime.h>
#include <hip/hip_bf16.h>
#include <math.h>

typedef unsigned short u16;
typedef __bf16 bf16x8 __attribute__((ext_vector_type(8)));
typedef float f32x4 __attribute__((ext_vector_type(4)));

#define NB 32
#define LSEQ 1024
#define DIN 512
#define EDIM 1024
#define SDIM 128
#define NTOK (NB * LSEQ)       // 32768
#define NUV 2176               // 2E + S
#define CHUNK 8                // batches per qk/pv chunk == #XCDs

__device__ __forceinline__ u16 f2bf(float f) {
  unsigned u = __builtin_bit_cast(unsigned, f);
  u += 0x7fffu + ((u >> 16) & 1u);
  return (u16)(u >> 16);
}
__device__ __forceinline__ float bf2f(u16 h) {
  unsigned u = ((unsigned)h) << 16;
  return __builtin_bit_cast(float, u);
}
// silu via hw exp2 + rcp (vs libm expf + divide)
__device__ __forceinline__ float fast_silu(float x) {
  float t = __builtin_amdgcn_exp2f(-1.44269504088896f * x);
  return x * __builtin_amdgcn_rcpf(1.0f + t);
}

// ---------------- small prep kernels ----------------

__global__ __launch_bounds__(256) void k_f32_to_bf16(const float* __restrict__ in,
                                                     u16* __restrict__ out, int n4) {
  int i = blockIdx.x * 256 + threadIdx.x;
  if (i < n4) {
    float4 f = ((const float4*)in)[i];
    ushort4 o;
    o.x = f2bf(f.x); o.y = f2bf(f.y); o.z = f2bf(f.z); o.w = f2bf(f.w);
    ((ushort4*)out)[i] = o;
  }
}

// fused rms-norm + half-shift: reads x once. Block t: own second half -> xn2[t],
// own (normalized) first half -> xn2[t+1] (if l<1023), zeros -> xn2[t] first
// half when l==0. Exactly one writer per output location.
__global__ __launch_bounds__(256) void k_normshift(const float* __restrict__ x,
                                                   const float* __restrict__ g,
                                                   u16* __restrict__ xn2) {
  int t = blockIdx.x;
  int l = t & (LSEQ - 1);
  float2 v = ((const float2*)(x + (size_t)t * DIN))[threadIdx.x];
  float ss = v.x * v.x + v.y * v.y;
  for (int o = 32; o > 0; o >>= 1) ss += __shfl_down(ss, o, 64);
  __shared__ float p[4];
  if ((threadIdx.x & 63) == 0) p[threadIdx.x >> 6] = ss;
  __syncthreads();
  float s = p[0] + p[1] + p[2] + p[3];
  float norm = sqrtf(s * (1.0f / (float)DIN));
  float inv = g[0] / fmaxf(norm, 1e-5f);
  int d = threadIdx.x * 2;
  ushort2 ob; ob.x = f2bf(v.x * inv); ob.y = f2bf(v.y * inv);
  if (d >= 256) {
    *(ushort2*)(xn2 + (size_t)t * DIN + d) = ob;                    // own 2nd half
  } else {
    if (l < LSEQ - 1) *(ushort2*)(xn2 + (size_t)(t + 1) * DIN + d) = ob;  // shifted
    if (l == 0) { ushort2 z = {0, 0}; *(ushort2*)(xn2 + (size_t)t * DIN + d) = z; }
  }
}

// RoPE tables in double precision (match numpy's correctly-rounded pow/sin)
__global__ __launch_bounds__(256) void k_rope_table(float* __restrict__ sin_t,
                                                    float* __restrict__ cos_t) {
  int idx = blockIdx.x * 256 + threadIdx.x;   // 1024*64
  int l = idx >> 6, j = idx & 63;
  double freq = pow(10000.0, (double)j / 64.0);
  float arg = (float)l * (float)freq;          // f32 product, matches np
  double a = (double)arg;
  sin_t[idx] = (float)sin(a);
  cos_t[idx] = (float)cos(a);
}

// base -> q,k with gamma/beta affine + RoPE
__global__ __launch_bounds__(256) void k_qkbuild(const u16* __restrict__ base,
                                                 const float* __restrict__ gamma,
                                                 const float* __restrict__ beta,
                                                 const float* __restrict__ sin_t,
                                                 const float* __restrict__ cos_t,
                                                 u16* __restrict__ q, u16* __restrict__ k) {
  int idx = blockIdx.x * 256 + threadIdx.x;   // NTOK*64
  int t = idx >> 6, j = idx & 63;
  int l = t & (LSEQ - 1);
  float b1 = bf2f(base[(size_t)t * SDIM + j]);
  float b2 = bf2f(base[(size_t)t * SDIM + j + 64]);
  float s = sin_t[l * 64 + j], c = cos_t[l * 64 + j];
  {
    float y1 = b1 * gamma[j] + beta[j];
    float y2 = b2 * gamma[64 + j] + beta[64 + j];
    q[(size_t)t * SDIM + j]      = f2bf(y1 * c - y2 * s);
    q[(size_t)t * SDIM + j + 64] = f2bf(y2 * c + y1 * s);
  }
  {
    float y1 = b1 * gamma[128 + j] + beta[128 + j];
    float y2 = b2 * gamma[192 + j] + beta[192 + j];
    k[(size_t)t * SDIM + j]      = f2bf(y1 * c - y2 * s);
    k[(size_t)t * SDIM + j + 64] = f2bf(y2 * c + y1 * s);
  }
}

// ---------------- GEMM core (TN, bf16 MFMA, 128x128 tile, BK=32) ----------------
// LDS: two buffers, each row-major [128][32] with the 16B k-slot XOR-swizzled by
// (row>>1)&3. Stage source permutes slots WITHIN each 64B row (coalescing kept);
// dest stays linear (global_load_lds requirement). Reader applies same XOR.

__device__ __forceinline__ void stage128x32(const u16* g, int ld, u16* l, int tid) {
  int r = tid >> 2;
  int c = ((tid & 3) ^ ((tid >> 3) & 3)) * 8;   // slot ^ ((r>>1)&3)
  const u16* g0 = g + (size_t)r * ld + c;
  const u16* g1 = g + (size_t)(r + 64) * ld + c;  // same mask (+64 rows: +32 ≡ 0 mod 4)
  u16* l0 = l + tid * 8;
  u16* l1 = l + tid * 8 + 2048;
  __builtin_amdgcn_global_load_lds((__attribute__((address_space(1))) unsigned int*)g0,
                                   (__attribute__((address_space(3))) unsigned int*)l0, 16, 0, 0);
  __builtin_amdgcn_global_load_lds((__attribute__((address_space(1))) unsigned int*)g1,
                                   (__attribute__((address_space(3))) unsigned int*)l1, 16, 0, 0);
}

// 2-phase double-buffered K-loop (T3-minimum): issue next-tile STAGE before the
// ds_read+MFMA of the current tile; ONE __syncthreads per iter (its built-in
// vmcnt(0)+lgkmcnt(0) drain is the fence both buffers need).
__device__ __forceinline__ void gemm_core(const u16* A, const u16* B, int K,
                                          int lda, int ldb,
                                          u16* sA, u16* sB, f32x4 acc[4][4]) {
  const int tid = threadIdx.x;
  const int lane = tid & 63;
  const int wid = tid >> 6;
  const int wr = wid >> 1, wc = wid & 1;
  const int fr = lane & 15, kg = lane >> 4;
  const int ks = (kg ^ ((fr >> 1) & 3)) * 8;    // swizzled k-slot (invariant to +16i, +64)
  const u16* sa_base = sA + (wr * 64 + fr) * 32 + ks;
  const u16* sb_base = sB + (wc * 64 + fr) * 32 + ks;
  const int nt = K >> 5;
  stage128x32(A, lda, sA, tid);
  stage128x32(B, ldb, sB, tid);
  __syncthreads();
  int cur = 0;
  for (int t = 0; t < nt; ++t) {
    if (t + 1 < nt) {
      stage128x32(A + (t + 1) * 32, lda, sA + ((cur ^ 1) << 12), tid);
      stage128x32(B + (t + 1) * 32, ldb, sB + ((cur ^ 1) << 12), tid);
    }
    const u16* sa = sa_base + (cur << 12);
    const u16* sb = sb_base + (cur << 12);
    bf16x8 a[4], b[4];
#pragma unroll
    for (int i = 0; i < 4; ++i) a[i] = *(const bf16x8*)(sa + i * 16 * 32);
#pragma unroll
    for (int i = 0; i < 4; ++i) b[i] = *(const bf16x8*)(sb + i * 16 * 32);
#pragma unroll
    for (int m = 0; m < 4; ++m)
#pragma unroll
      for (int n = 0; n < 4; ++n)
        acc[m][n] = __builtin_amdgcn_mfma_f32_16x16x32_bf16(a[m], b[n], acc[m][n], 0, 0, 0);
    __syncthreads();
    cur ^= 1;
  }
}

// C/D layout: col = lane&15 (+n*16), row = (lane>>4)*4 + j (+m*16)

// GEMM1: uv = silu(xn2 @ uv_w^T); u [tok][e], v stored transposed per-batch
// vt[b][e][l], base [tok][s].  Grid 4352 = 8 XCDs x 32 M-tiles x 17 N-tiles.
__global__ __launch_bounds__(256) void k_gemm_uv(const u16* __restrict__ xn2,
                                                 const u16* __restrict__ wbf,
                                                 u16* __restrict__ u, u16* __restrict__ vt,
                                                 u16* __restrict__ base) {
  __shared__ __align__(16) u16 sA[8192];
  __shared__ __align__(16) u16 sB[8192];
  f32x4 acc[4][4] = {};
  int bid = blockIdx.x;
  int xcd = bid & 7;
  int off = bid >> 3;                 // 0..543
  int m0 = (xcd * 32 + off / 17) * 128;
  int n0 = (off % 17) * 128;
  gemm_core(xn2 + (size_t)m0 * DIN, wbf + (size_t)n0 * DIN, DIN, DIN, DIN, sA, sB, acc);
  int lane = threadIdx.x & 63, wid = threadIdx.x >> 6;
  int wr = wid >> 1, wc = wid & 1;
  int cb = n0 + wc * 64 + (lane & 15);
  int rb = m0 + wr * 64 + (lane >> 4) * 4;
  if (n0 < EDIM) {                       // u columns
#pragma unroll
    for (int m = 0; m < 4; ++m)
#pragma unroll
      for (int n = 0; n < 4; ++n) {
        int c = cb + n * 16;
#pragma unroll
        for (int j = 0; j < 4; ++j) {
          int r = rb + m * 16 + j;
          u[(size_t)r * EDIM + c] = f2bf(fast_silu(acc[m][n][j]));
        }
      }
  } else if (n0 < 2 * EDIM) {            // v columns -> transposed store
    int b = m0 >> 10;
    u16* vtb = vt + (size_t)b * (EDIM * LSEQ);
#pragma unroll
    for (int m = 0; m < 4; ++m) {
      int l0 = (rb + m * 16) & (LSEQ - 1);
#pragma unroll
      for (int n = 0; n < 4; ++n) {
        int e = cb + n * 16 - EDIM;
        ushort4 o;
        o.x = f2bf(fast_silu(acc[m][n][0]));
        o.y = f2bf(fast_silu(acc[m][n][1]));
        o.z = f2bf(fast_silu(acc[m][n][2]));
        o.w = f2bf(fast_silu(acc[m][n][3]));
        *(ushort4*)(vtb + (size_t)e * LSEQ + l0) = o;
      }
    }
  } else {                               // base columns
#pragma unroll
    for (int m = 0; m < 4; ++m)
#pragma unroll
      for (int n = 0; n < 4; ++n) {
        int c = cb + n * 16 - 2 * EDIM;
#pragma unroll
        for (int j = 0; j < 4; ++j) {
          int r = rb + m * 16 + j;
          base[(size_t)r * SDIM + c] = f2bf(fast_silu(acc[m][n][j]));
        }
      }
  }
}

// GEMM2: scores = relu((q k^T + w)/sqrt(S))^2.  Grid 512 = 8 batches(->XCDs) x 64
// tiles; q[b]/k[b] (256KB each) L2-resident per XCD.
__global__ __launch_bounds__(256) void k_gemm_qk(const u16* __restrict__ q,
                                                 const u16* __restrict__ k,
                                                 const float* __restrict__ w,
                                                 u16* __restrict__ scores) {
  __shared__ __align__(16) u16 sA[8192];
  __shared__ __align__(16) u16 sB[8192];
  f32x4 acc[4][4] = {};
  int bid = blockIdx.x;
  int b = bid & 7;                       // chunk-local batch == XCD
  int off = bid >> 3;                    // 0..63
  int m0 = (off >> 3) * 128, n0 = (off & 7) * 128;
  gemm_core(q + (size_t)(b * LSEQ + m0) * SDIM, k + (size_t)(b * LSEQ + n0) * SDIM,
            SDIM, SDIM, SDIM, sA, sB, acc);
  int lane = threadIdx.x & 63, wid = threadIdx.x >> 6;
  int wr = wid >> 1, wc = wid & 1;
  int cb = n0 + wc * 64 + (lane & 15);
  int rb = m0 + wr * 64 + (lane >> 4) * 4;
  const float inv_sqrt_s = 0.08838834764831845f;
  u16* sc_b = scores + (size_t)b * LSEQ * LSEQ;
#pragma unroll
  for (int m = 0; m < 4; ++m)
#pragma unroll
    for (int n = 0; n < 4; ++n) {
      int c = cb + n * 16;
#pragma unroll
      for (int j = 0; j < 4; ++j) {
        int r = rb + m * 16 + j;
        float val = (acc[m][n][j] + w[c - r + (LSEQ - 1)]) * inv_sqrt_s;
        val = fmaxf(val, 0.0f);
        sc_b[(size_t)r * LSEQ + c] = f2bf(val * val);
      }
    }
}

// GEMM3: u_io <- u_io .* (scores @ v).  Grid 512 = 8 batches(->XCDs) x 64 tiles;
// scores[b] (2MB) + vt[b] (2MB) fit one XCD's 4MB L2.
__global__ __launch_bounds__(256) void k_gemm_pv(const u16* __restrict__ scores,
                                                 const u16* __restrict__ vt,
                                                 u16* u_io) {
  __shared__ __align__(16) u16 sA[8192];
  __shared__ __align__(16) u16 sB[8192];
  f32x4 acc[4][4] = {};
  int bid = blockIdx.x;
  int b = bid & 7;                       // chunk-local batch == XCD
  int off = bid >> 3;                    // 0..63
  int m0 = (off >> 3) * 128, n0 = (off & 7) * 128;
  gemm_core(scores + (size_t)b * LSEQ * LSEQ + (size_t)m0 * LSEQ,
            vt + (size_t)b * LSEQ * EDIM + (size_t)n0 * LSEQ,
            LSEQ, LSEQ, LSEQ, sA, sB, acc);
  int lane = threadIdx.x & 63, wid = threadIdx.x >> 6;
  int wr = wid >> 1, wc = wid & 1;
  int cb = n0 + wc * 64 + (lane & 15);
  int rb = m0 + wr * 64 + (lane >> 4) * 4;
#pragma unroll
  for (int m = 0; m < 4; ++m)
#pragma unroll
    for (int n = 0; n < 4; ++n) {
      int c = cb + n * 16;
#pragma unroll
      for (int j = 0; j < 4; ++j) {
        int r = rb + m * 16 + j;
        size_t idx = (size_t)(b * LSEQ + r) * EDIM + c;
        u_io[idx] = f2bf(acc[m][n][j] * bf2f(u_io[idx]));  // same thread reads+writes
      }
    }
}

// GEMM4: out = x*res_scale + (attn @ o_w^T)*layer_scale.  Grid 1024 = 8x32x4.
__global__ __launch_bounds__(256) void k_gemm_out(const u16* __restrict__ attn,
                                                  const u16* __restrict__ owbf,
                                                  const float* __restrict__ x,
                                                  const float* __restrict__ res_scale,
                                                  const float* __restrict__ layer_scale,
                                                  float* __restrict__ out) {
  __shared__ __align__(16) u16 sA[8192];
  __shared__ __align__(16) u16 sB[8192];
  f32x4 acc[4][4] = {};
  int bid = blockIdx.x;
  int xcd = bid & 7;
  int off = bid >> 3;                 // 0..127
  int m0 = (xcd * 32 + (off >> 2)) * 128;
  int n0 = (off & 3) * 128;
  gemm_core(attn + (size_t)m0 * EDIM, owbf + (size_t)n0 * EDIM, EDIM, EDIM, EDIM, sA, sB, acc);
  int lane = threadIdx.x & 63, wid = threadIdx.x >> 6;
  int wr = wid >> 1, wc = wid & 1;
  int cb = n0 + wc * 64 + (lane & 15);
  int rb = m0 + wr * 64 + (lane >> 4) * 4;
#pragma unroll
  for (int m = 0; m < 4; ++m)
#pragma unroll
    for (int n = 0; n < 4; ++n) {
      int c = cb + n * 16;
#pragma unroll
      for (int j = 0; j < 4; ++j) {
        int r = rb + m * 16 + j;
        out[(size_t)r * DIN + c] =
            x[(size_t)r * DIN + c] * res_scale[c] + acc[m][n][j] * layer_scale[c];
      }
    }
}

// ---------------- launch ----------------

extern "C" void kernel_launch(void* const* d_in, const int* in_sizes, int n_in,
                              void* d_out, int out_size, void* d_ws, size_t ws_size,
                              hipStream_t stream) {
  const float* x          = (const float*)d_in[0];
  const float* uv_w       = (const float*)d_in[1];
  const float* o_w        = (const float*)d_in[2];
  const float* gamma      = (const float*)d_in[3];
  const float* beta       = (const float*)d_in[4];
  const float* w          = (const float*)d_in[5];
  const float* g          = (const float*)d_in[6];
  const float* res_scale  = (const float*)d_in[7];
  const float* layer_scale= (const float*)d_in[8];
  float* out = (float*)d_out;

  char* ws = (char*)d_ws;
  // workspace layout (bytes), peak ~197 MB (known-good):
  u16* xn2    = (u16*)(ws + 0);           // 32 MB, dead after gemm_uv
  u16* q      = (u16*)(ws + 0);           // 8 MB, aliases dead xn2
  u16* k      = (u16*)(ws + 8388608);     // 8 MB, aliases dead xn2
  u16* base   = (u16*)(ws + 33554432);    // 8 MB, live gemm_uv -> qkbuild
  u16* u_io   = (u16*)(ws + 41943040);    // 64 MB: u, gated in place -> attn
  u16* vt     = (u16*)(ws + 109051904);   // 64 MB: v^T per batch
  u16* scores = (u16*)(ws + 176160768);   // 16 MB (one 8-batch chunk)
  u16* uvw_bf = (u16*)(ws + 192937984);   // 2.125 MB
  u16* ow_bf  = (u16*)(ws + 195166208);   // 1 MB
  float* sin_t   = (float*)(ws + 196345856);  // 256 KB
  float* cos_t   = (float*)(ws + 196608000);  // 256 KB

  // prep
  k_f32_to_bf16<<<dim3((NUV * DIN / 4 + 255) / 256), 256, 0, stream>>>(uv_w, uvw_bf, NUV * DIN / 4);
  k_f32_to_bf16<<<dim3((DIN * EDIM / 4 + 255) / 256), 256, 0, stream>>>(o_w, ow_bf, DIN * EDIM / 4);
  k_rope_table<<<dim3(LSEQ * 64 / 256), 256, 0, stream>>>(sin_t, cos_t);
  k_normshift<<<dim3(NTOK), 256, 0, stream>>>(x, g, xn2);

  // uv projection + silu (v written transposed)
  k_gemm_uv<<<dim3(4352), 256, 0, stream>>>(xn2, uvw_bf, u_io, vt, base);

  // q,k build (writes into dead xn2 region)
  k_qkbuild<<<dim3(NTOK * 64 / 256), 256, 0, stream>>>(base, gamma, beta, sin_t, cos_t, q, k);

  // scores + pv, chunked by 8 batches (scores buffer = 16 MB, reused)
  for (int ch = 0; ch < NB / CHUNK; ++ch) {
    size_t tok0 = (size_t)ch * CHUNK * LSEQ;
    k_gemm_qk<<<dim3(512), 256, 0, stream>>>(q + tok0 * SDIM, k + tok0 * SDIM, w, scores);
    k_gemm_pv<<<dim3(512), 256, 0, stream>>>(scores, vt + tok0 * EDIM, u_io + tok0 * EDIM);
  }

  // final projection + residual
  k_gemm_out<<<dim3(1024), 256, 0, stream>>>(u_io, ow_bf, x, res_scale, layer_scale, out);
}

// Round 6
// 331.894 us; speedup vs baseline: 1.3208x; 1.3208x over previous
//
#include <hip/hip_runtime.h>
#include <hip/hip_bf16.h>
#include <math.h>

typedef unsigned short u16;
typedef __bf16 bf16x8 __attribute__((ext_vector_type(8)));
typedef float f32x4 __attribute__((ext_vector_type(4)));

#define NB 32
#define LSEQ 1024
#define DIN 512
#define EDIM 1024
#define SDIM 128
#define NTOK (NB * LSEQ)       // 32768
#define NUV 2176               // 2E + S
#define CHUNK 16               // batches per qk/pv chunk

#define AS1 __attribute__((address_space(1)))
#define AS3 __attribute__((address_space(3)))

__device__ __forceinline__ u16 f2bf(float f) {
  unsigned u = __builtin_bit_cast(unsigned, f);
  u += 0x7fffu + ((u >> 16) & 1u);
  return (u16)(u >> 16);
}
__device__ __forceinline__ float bf2f(u16 h) {
  unsigned u = ((unsigned)h) << 16;
  return __builtin_bit_cast(float, u);
}
__device__ __forceinline__ float fast_silu(float x) {
  float t = __builtin_amdgcn_exp2f(-1.44269504088896f * x);
  return x * __builtin_amdgcn_rcpf(1.0f + t);
}

// ---------------- small prep kernels ----------------

__global__ __launch_bounds__(256) void k_f32_to_bf16(const float* __restrict__ in,
                                                     u16* __restrict__ out, int n4) {
  int i = blockIdx.x * 256 + threadIdx.x;
  if (i < n4) {
    float4 f = ((const float4*)in)[i];
    ushort4 o;
    o.x = f2bf(f.x); o.y = f2bf(f.y); o.z = f2bf(f.z); o.w = f2bf(f.w);
    ((ushort4*)out)[i] = o;
  }
}

// fused rms-norm + half-shift (reads x once; verified R5)
__global__ __launch_bounds__(256) void k_normshift(const float* __restrict__ x,
                                                   const float* __restrict__ g,
                                                   u16* __restrict__ xn2) {
  int t = blockIdx.x;
  int l = t & (LSEQ - 1);
  float2 v = ((const float2*)(x + (size_t)t * DIN))[threadIdx.x];
  float ss = v.x * v.x + v.y * v.y;
  for (int o = 32; o > 0; o >>= 1) ss += __shfl_down(ss, o, 64);
  __shared__ float p[4];
  if ((threadIdx.x & 63) == 0) p[threadIdx.x >> 6] = ss;
  __syncthreads();
  float s = p[0] + p[1] + p[2] + p[3];
  float norm = sqrtf(s * (1.0f / (float)DIN));
  float inv = g[0] / fmaxf(norm, 1e-5f);
  int d = threadIdx.x * 2;
  ushort2 ob; ob.x = f2bf(v.x * inv); ob.y = f2bf(v.y * inv);
  if (d >= 256) {
    *(ushort2*)(xn2 + (size_t)t * DIN + d) = ob;
  } else {
    if (l < LSEQ - 1) *(ushort2*)(xn2 + (size_t)(t + 1) * DIN + d) = ob;
    if (l == 0) { ushort2 z = {0, 0}; *(ushort2*)(xn2 + (size_t)t * DIN + d) = z; }
  }
}

// RoPE tables in double precision (match numpy)
__global__ __launch_bounds__(256) void k_rope_table(float* __restrict__ sin_t,
                                                    float* __restrict__ cos_t) {
  int idx = blockIdx.x * 256 + threadIdx.x;   // 1024*64
  int l = idx >> 6, j = idx & 63;
  double freq = pow(10000.0, (double)j / 64.0);
  float arg = (float)l * (float)freq;
  double a = (double)arg;
  sin_t[idx] = (float)sin(a);
  cos_t[idx] = (float)cos(a);
}

// base -> q,k with gamma/beta affine + RoPE
__global__ __launch_bounds__(256) void k_qkbuild(const u16* __restrict__ base,
                                                 const float* __restrict__ gamma,
                                                 const float* __restrict__ beta,
                                                 const float* __restrict__ sin_t,
                                                 const float* __restrict__ cos_t,
                                                 u16* __restrict__ q, u16* __restrict__ k) {
  int idx = blockIdx.x * 256 + threadIdx.x;   // NTOK*64
  int t = idx >> 6, j = idx & 63;
  int l = t & (LSEQ - 1);
  float b1 = bf2f(base[(size_t)t * SDIM + j]);
  float b2 = bf2f(base[(size_t)t * SDIM + j + 64]);
  float s = sin_t[l * 64 + j], c = cos_t[l * 64 + j];
  {
    float y1 = b1 * gamma[j] + beta[j];
    float y2 = b2 * gamma[64 + j] + beta[64 + j];
    q[(size_t)t * SDIM + j]      = f2bf(y1 * c - y2 * s);
    q[(size_t)t * SDIM + j + 64] = f2bf(y2 * c + y1 * s);
  }
  {
    float y1 = b1 * gamma[128 + j] + beta[128 + j];
    float y2 = b2 * gamma[192 + j] + beta[192 + j];
    k[(size_t)t * SDIM + j]      = f2bf(y1 * c - y2 * s);
    k[(size_t)t * SDIM + j + 64] = f2bf(y2 * c + y1 * s);
  }
}

// ============ 128x128 1-phase core (R4-verified) — used by qk only ============

__device__ __forceinline__ void stage128x32(const u16* g, int ld, u16* l, int tid) {
  int r = tid >> 2;
  int c = ((tid & 3) ^ ((tid >> 3) & 3)) * 8;
  const u16* g0 = g + (size_t)r * ld + c;
  const u16* g1 = g + (size_t)(r + 64) * ld + c;
  u16* l0 = l + tid * 8;
  u16* l1 = l + tid * 8 + 2048;
  __builtin_amdgcn_global_load_lds((AS1 unsigned int*)g0, (AS3 unsigned int*)l0, 16, 0, 0);
  __builtin_amdgcn_global_load_lds((AS1 unsigned int*)g1, (AS3 unsigned int*)l1, 16, 0, 0);
}

__device__ __forceinline__ void gemm_core(const u16* A, const u16* B, int K,
                                          int lda, int ldb,
                                          u16* sA, u16* sB, f32x4 acc[4][4]) {
  const int tid = threadIdx.x;
  const int lane = tid & 63;
  const int wid = tid >> 6;
  const int wr = wid >> 1, wc = wid & 1;
  const int fr = lane & 15, kg = lane >> 4;
  const int ks = (kg ^ ((fr >> 1) & 3)) * 8;
  const u16* sa_base = sA + (wr * 64 + fr) * 32 + ks;
  const u16* sb_base = sB + (wc * 64 + fr) * 32 + ks;
  for (int k0 = 0; k0 < K; k0 += 32) {
    stage128x32(A + k0, lda, sA, tid);
    stage128x32(B + k0, ldb, sB, tid);
    __syncthreads();
    bf16x8 a[4], b[4];
#pragma unroll
    for (int i = 0; i < 4; ++i) a[i] = *(const bf16x8*)(sa_base + i * 16 * 32);
#pragma unroll
    for (int i = 0; i < 4; ++i) b[i] = *(const bf16x8*)(sb_base + i * 16 * 32);
#pragma unroll
    for (int m = 0; m < 4; ++m)
#pragma unroll
      for (int n = 0; n < 4; ++n)
        acc[m][n] = __builtin_amdgcn_mfma_f32_16x16x32_bf16(a[m], b[n], acc[m][n], 0, 0, 0);
    __syncthreads();
  }
}

// ============ 256x256 8-wave pipelined core (T2+T3+T4+T5) ============
// 512 threads = 8 waves (2M x 4N). BK=64. LDS 128 KB = 2 bufs x (A 32K + B 32K).
// LDS tile layout: [256 rows][8 slots of 8 elems], slot XOR-swizzled by row&7
// (read-side XOR + inverse-permuted global source within each 128B row).
// Counted vmcnt(8): 2 K-tiles in flight, never drains to 0 in steady state.

__device__ __forceinline__ void stage256x64(const u16* __restrict__ g, int ld,
                                            u16* __restrict__ lds, int tid) {
#pragma unroll
  for (int j = 0; j < 4; ++j) {
    int idx = tid + j * 512;
    int row = idx >> 3;
    int sc = ((idx & 7) ^ (row & 7)) * 8;
    const u16* src = g + (size_t)row * ld + sc;
    __builtin_amdgcn_global_load_lds((AS1 unsigned int*)src,
                                     (AS3 unsigned int*)(lds + idx * 8), 16, 0, 0);
  }
}

__device__ __forceinline__ void gemm256_core(const u16* A, int lda,
                                             const u16* B, int ldb,
                                             int K, u16* smem, f32x4 (&acc)[8][4]) {
  const int tid = threadIdx.x;
  const int lane = tid & 63, wid = tid >> 6;
  const int wr = wid >> 2, wc = wid & 3;     // 2M x 4N waves
  const int fr = lane & 15, kg = lane >> 4;
  u16* A0 = smem;
  u16* B0 = smem + 16384;
  u16* A1 = smem + 32768;
  u16* B1 = smem + 49152;
  const int nt = K >> 6;
  stage256x64(A, lda, A0, tid);
  stage256x64(B, ldb, B0, tid);
  stage256x64(A + 64, lda, A1, tid);
  stage256x64(B + 64, ldb, B1, tid);
  asm volatile("s_waitcnt vmcnt(8)" ::: "memory");   // tile 0 landed
  __builtin_amdgcn_sched_barrier(0);
  __builtin_amdgcn_s_barrier();
  for (int t = 0; t < nt; ++t) {
    u16* cA = (t & 1) ? A1 : A0;
    u16* cB = (t & 1) ? B1 : B0;
    bf16x8 b[4][2];
#pragma unroll
    for (int q = 0; q < 4; ++q) {
      bf16x8 a[2][2];
#pragma unroll
      for (int r = 0; r < 2; ++r)
#pragma unroll
        for (int h = 0; h < 2; ++h) {
          int row = wr * 128 + (q * 2 + r) * 16 + fr;
          int slot = (h * 4 + kg) ^ (fr & 7);
          a[r][h] = *(const bf16x8*)(cA + row * 64 + slot * 8);
        }
      if (q == 0) {
#pragma unroll
        for (int n = 0; n < 4; ++n)
#pragma unroll
          for (int h = 0; h < 2; ++h) {
            int row = wc * 64 + n * 16 + fr;
            int slot = (h * 4 + kg) ^ (fr & 7);
            b[n][h] = *(const bf16x8*)(cB + row * 64 + slot * 8);
          }
      }
      __builtin_amdgcn_s_barrier();
      __builtin_amdgcn_s_setprio(1);
#pragma unroll
      for (int r = 0; r < 2; ++r)
#pragma unroll
        for (int n = 0; n < 4; ++n)
#pragma unroll
          for (int h = 0; h < 2; ++h)
            acc[q * 2 + r][n] = __builtin_amdgcn_mfma_f32_16x16x32_bf16(
                a[r][h], b[n][h], acc[q * 2 + r][n], 0, 0, 0);
      __builtin_amdgcn_s_setprio(0);
      __builtin_amdgcn_s_barrier();
    }
    // all waves done reading buf(t&1): refill it with tile t+2
    if (t + 2 < nt) {
      stage256x64(A + (size_t)(t + 2) * 64, lda, cA, tid);
      stage256x64(B + (size_t)(t + 2) * 64, ldb, cB, tid);
      asm volatile("s_waitcnt vmcnt(8)" ::: "memory");  // tile t+1 landed
    } else {
      asm volatile("s_waitcnt vmcnt(0)" ::: "memory");  // epilogue drain
    }
    __builtin_amdgcn_sched_barrier(0);
    __builtin_amdgcn_s_barrier();
  }
}

// GEMM1: uv = silu(xn2 @ uv_w^T). Grid 1152 = 8 XCDs x 16 M-tiles x 9 N-tiles.
// N-tiles 0-3 -> u [tok][e]; 4-7 -> v transposed per-batch vt[b][e][l];
// tile 8 -> base (cols 2048..2175; wc>=2 discarded; B-rows 2176..2303 read
// from the padded region after uvw_bf — garbage, never stored).
__global__ __launch_bounds__(512, 2) void k_gemm_uv(const u16* __restrict__ xn2,
                                                    const u16* __restrict__ wbf,
                                                    u16* __restrict__ u, u16* __restrict__ vt,
                                                    u16* __restrict__ base) {
  __shared__ __align__(16) u16 smem[65536];
  f32x4 acc[8][4] = {};
  int bid = blockIdx.x;
  int xcd = bid & 7;
  int off = bid >> 3;                 // 0..143
  int m0 = (xcd * 16 + off / 9) * 256;
  int n0 = (off % 9) * 256;
  gemm256_core(xn2 + (size_t)m0 * DIN, DIN, wbf + (size_t)n0 * DIN, DIN, DIN, smem, acc);
  int lane = threadIdx.x & 63, wid = threadIdx.x >> 6;
  int wr = wid >> 2, wc = wid & 3;
  int cb = n0 + wc * 64 + (lane & 15);
  int rb = m0 + wr * 128 + (lane >> 4) * 4;
  if (n0 < EDIM) {                       // u columns
#pragma unroll
    for (int mm = 0; mm < 8; ++mm)
#pragma unroll
      for (int n = 0; n < 4; ++n) {
        int c = cb + n * 16;
#pragma unroll
        for (int j = 0; j < 4; ++j) {
          int r = rb + mm * 16 + j;
          u[(size_t)r * EDIM + c] = f2bf(fast_silu(acc[mm][n][j]));
        }
      }
  } else if (n0 < 2 * EDIM) {            // v columns -> transposed store
    int b = m0 >> 10;
    u16* vtb = vt + (size_t)b * (EDIM * LSEQ);
#pragma unroll
    for (int mm = 0; mm < 8; ++mm) {
      int l0 = (rb + mm * 16) & (LSEQ - 1);
#pragma unroll
      for (int n = 0; n < 4; ++n) {
        int e = cb + n * 16 - EDIM;
        ushort4 o;
        o.x = f2bf(fast_silu(acc[mm][n][0]));
        o.y = f2bf(fast_silu(acc[mm][n][1]));
        o.z = f2bf(fast_silu(acc[mm][n][2]));
        o.w = f2bf(fast_silu(acc[mm][n][3]));
        *(ushort4*)(vtb + (size_t)e * LSEQ + l0) = o;
      }
    }
  } else if (wc < 2) {                   // base columns (valid half-tile)
#pragma unroll
    for (int mm = 0; mm < 8; ++mm)
#pragma unroll
      for (int n = 0; n < 4; ++n) {
        int c = cb + n * 16 - 2 * EDIM;
#pragma unroll
        for (int j = 0; j < 4; ++j) {
          int r = rb + mm * 16 + j;
          base[(size_t)r * SDIM + c] = f2bf(fast_silu(acc[mm][n][j]));
        }
      }
  }
}

// GEMM2: scores = relu((q k^T + w)/sqrt(S))^2.  128^2 1-phase core.
// Grid 1024 = 8 XCDs x 2 batches x 64 tiles (16 batches per launch).
__global__ __launch_bounds__(256) void k_gemm_qk(const u16* __restrict__ q,
                                                 const u16* __restrict__ k,
                                                 const float* __restrict__ w,
                                                 u16* __restrict__ scores) {
  __shared__ __align__(16) u16 sA[4096];
  __shared__ __align__(16) u16 sB[4096];
  f32x4 acc[4][4] = {};
  int bid = blockIdx.x;
  int xcd = bid & 7;
  int off = bid >> 3;                    // 0..127
  int b = xcd * 2 + (off >> 6);          // chunk-local batch
  int t = off & 63;
  int m0 = (t >> 3) * 128, n0 = (t & 7) * 128;
  gemm_core(q + (size_t)(b * LSEQ + m0) * SDIM, k + (size_t)(b * LSEQ + n0) * SDIM,
            SDIM, SDIM, SDIM, sA, sB, acc);
  int lane = threadIdx.x & 63, wid = threadIdx.x >> 6;
  int wr = wid >> 1, wc = wid & 1;
  int cb = n0 + wc * 64 + (lane & 15);
  int rb = m0 + wr * 64 + (lane >> 4) * 4;
  const float inv_sqrt_s = 0.08838834764831845f;
  u16* sc_b = scores + (size_t)b * LSEQ * LSEQ;
#pragma unroll
  for (int m = 0; m < 4; ++m)
#pragma unroll
    for (int n = 0; n < 4; ++n) {
      int c = cb + n * 16;
#pragma unroll
      for (int j = 0; j < 4; ++j) {
        int r = rb + m * 16 + j;
        float val = (acc[m][n][j] + w[c - r + (LSEQ - 1)]) * inv_sqrt_s;
        val = fmaxf(val, 0.0f);
        sc_b[(size_t)r * LSEQ + c] = f2bf(val * val);
      }
    }
}

// GEMM3: u_io <- u_io .* (scores @ v).  256^2 core.
// Grid 256 = 8 XCDs x 2 batches x 16 tiles (16 batches per launch).
__global__ __launch_bounds__(512, 2) void k_gemm_pv(const u16* __restrict__ scores,
                                                    const u16* __restrict__ vt,
                                                    u16* u_io) {
  __shared__ __align__(16) u16 smem[65536];
  f32x4 acc[8][4] = {};
  int bid = blockIdx.x;
  int xcd = bid & 7;
  int off = bid >> 3;                    // 0..31
  int b = xcd * 2 + (off >> 4);          // chunk-local batch
  int t = off & 15;
  int m0 = (t >> 2) * 256, n0 = (t & 3) * 256;
  gemm256_core(scores + (size_t)b * LSEQ * LSEQ + (size_t)m0 * LSEQ, LSEQ,
               vt + (size_t)b * LSEQ * EDIM + (size_t)n0 * LSEQ, LSEQ,
               LSEQ, smem, acc);
  int lane = threadIdx.x & 63, wid = threadIdx.x >> 6;
  int wr = wid >> 2, wc = wid & 3;
  int cb = n0 + wc * 64 + (lane & 15);
  int rb = m0 + wr * 128 + (lane >> 4) * 4;
#pragma unroll
  for (int mm = 0; mm < 8; ++mm)
#pragma unroll
    for (int n = 0; n < 4; ++n) {
      int c = cb + n * 16;
#pragma unroll
      for (int j = 0; j < 4; ++j) {
        int r = rb + mm * 16 + j;
        size_t idx = (size_t)(b * LSEQ + r) * EDIM + c;
        u_io[idx] = f2bf(acc[mm][n][j] * bf2f(u_io[idx]));
      }
    }
}

// GEMM4: out = x*res_scale + (attn @ o_w^T)*layer_scale.  256^2 core.
// Grid 256 = 8 XCDs x 16 M-tiles x 2 N-tiles.
__global__ __launch_bounds__(512, 2) void k_gemm_out(const u16* __restrict__ attn,
                                                     const u16* __restrict__ owbf,
                                                     const float* __restrict__ x,
                                                     const float* __restrict__ res_scale,
                                                     const float* __restrict__ layer_scale,
                                                     float* __restrict__ out) {
  __shared__ __align__(16) u16 smem[65536];
  f32x4 acc[8][4] = {};
  int bid = blockIdx.x;
  int xcd = bid & 7;
  int off = bid >> 3;                 // 0..31
  int m0 = (xcd * 16 + (off >> 1)) * 256;
  int n0 = (off & 1) * 256;
  gemm256_core(attn + (size_t)m0 * EDIM, EDIM, owbf + (size_t)n0 * EDIM, EDIM,
               EDIM, smem, acc);
  int lane = threadIdx.x & 63, wid = threadIdx.x >> 6;
  int wr = wid >> 2, wc = wid & 3;
  int cb = n0 + wc * 64 + (lane & 15);
  int rb = m0 + wr * 128 + (lane >> 4) * 4;
#pragma unroll
  for (int mm = 0; mm < 8; ++mm)
#pragma unroll
    for (int n = 0; n < 4; ++n) {
      int c = cb + n * 16;
#pragma unroll
      for (int j = 0; j < 4; ++j) {
        int r = rb + mm * 16 + j;
        out[(size_t)r * DIN + c] =
            x[(size_t)r * DIN + c] * res_scale[c] + acc[mm][n][j] * layer_scale[c];
      }
    }
}

// ---------------- launch ----------------

extern "C" void kernel_launch(void* const* d_in, const int* in_sizes, int n_in,
                              void* d_out, int out_size, void* d_ws, size_t ws_size,
                              hipStream_t stream) {
  const float* x          = (const float*)d_in[0];
  const float* uv_w       = (const float*)d_in[1];
  const float* o_w        = (const float*)d_in[2];
  const float* gamma      = (const float*)d_in[3];
  const float* beta       = (const float*)d_in[4];
  const float* w          = (const float*)d_in[5];
  const float* g          = (const float*)d_in[6];
  const float* res_scale  = (const float*)d_in[7];
  const float* layer_scale= (const float*)d_in[8];
  float* out = (float*)d_out;

  char* ws = (char*)d_ws;
  // workspace layout (bytes), peak ~180 MB (< proven-good 197):
  u16* xn2    = (u16*)(ws + 0);            // 32 MB, dead after gemm_uv
  u16* q      = (u16*)(ws + 0);            // 8 MB (aliases dead xn2)
  u16* k      = (u16*)(ws + 8388608);      // 8 MB (aliases dead xn2)
  u16* scores = (u16*)(ws + 16777216);     // 32 MB (aliases dead xn2-upper + dead base)
  u16* base   = (u16*)(ws + 33554432);     // 8 MB, live gemm_uv -> qkbuild
  u16* u_io   = (u16*)(ws + 50331648);     // 64 MB: u, gated in place -> attn
  u16* vt     = (u16*)(ws + 117440512);    // 64 MB: v^T per batch
  u16* uvw_bf = (u16*)(ws + 184549376);    // 2.125 MB (+0.125 MB pad-read slack)
  u16* ow_bf  = (u16*)(ws + 186908672);    // 1 MB
  float* sin_t = (float*)(ws + 187957248); // 256 KB
  float* cos_t = (float*)(ws + 188219392); // 256 KB

  // prep
  k_f32_to_bf16<<<dim3((NUV * DIN / 4 + 255) / 256), 256, 0, stream>>>(uv_w, uvw_bf, NUV * DIN / 4);
  k_f32_to_bf16<<<dim3((DIN * EDIM / 4 + 255) / 256), 256, 0, stream>>>(o_w, ow_bf, DIN * EDIM / 4);
  k_rope_table<<<dim3(LSEQ * 64 / 256), 256, 0, stream>>>(sin_t, cos_t);
  k_normshift<<<dim3(NTOK), 256, 0, stream>>>(x, g, xn2);

  // uv projection + silu (256^2 pipelined core)
  k_gemm_uv<<<dim3(1152), 512, 0, stream>>>(xn2, uvw_bf, u_io, vt, base);

  // q,k build (writes into dead xn2 region)
  k_qkbuild<<<dim3(NTOK * 64 / 256), 256, 0, stream>>>(base, gamma, beta, sin_t, cos_t, q, k);

  // scores + pv, chunked by 16 batches
  for (int ch = 0; ch < NB / CHUNK; ++ch) {
    size_t tok0 = (size_t)ch * CHUNK * LSEQ;
    k_gemm_qk<<<dim3(1024), 256, 0, stream>>>(q + tok0 * SDIM, k + tok0 * SDIM, w, scores);
    k_gemm_pv<<<dim3(256), 512, 0, stream>>>(scores, vt + tok0 * EDIM, u_io + tok0 * EDIM);
  }

  // final projection + residual (256^2 core)
  k_gemm_out<<<dim3(256), 512, 0, stream>>>(u_io, ow_bf, x, res_scale, layer_scale, out);
}

// Round 7
// 318.516 us; speedup vs baseline: 1.3763x; 1.0420x over previous
//
#include <hip/hip_runtime.h>
#include <hip/hip_bf16.h>
#include <math.h>

typedef unsigned short u16;
typedef __bf16 bf16x8 __attribute__((ext_vector_type(8)));
typedef float f32x4 __attribute__((ext_vector_type(4)));

#define NB 32
#define LSEQ 1024
#define DIN 512
#define EDIM 1024
#define SDIM 128
#define NTOK (NB * LSEQ)       // 32768
#define NUV 2176               // 2E + S
#define CHUNK 16               // batches per qk/pv chunk

#define AS1 __attribute__((address_space(1)))
#define AS3 __attribute__((address_space(3)))

__device__ __forceinline__ u16 f2bf(float f) {
  unsigned u = __builtin_bit_cast(unsigned, f);
  u += 0x7fffu + ((u >> 16) & 1u);
  return (u16)(u >> 16);
}
__device__ __forceinline__ float bf2f(u16 h) {
  unsigned u = ((unsigned)h) << 16;
  return __builtin_bit_cast(float, u);
}
__device__ __forceinline__ float fast_silu(float x) {
  float t = __builtin_amdgcn_exp2f(-1.44269504088896f * x);
  return x * __builtin_amdgcn_rcpf(1.0f + t);
}

// ---------------- small prep kernels ----------------

__global__ __launch_bounds__(256) void k_f32_to_bf16(const float* __restrict__ in,
                                                     u16* __restrict__ out, int n4) {
  int i = blockIdx.x * 256 + threadIdx.x;
  if (i < n4) {
    float4 f = ((const float4*)in)[i];
    ushort4 o;
    o.x = f2bf(f.x); o.y = f2bf(f.y); o.z = f2bf(f.z); o.w = f2bf(f.w);
    ((ushort4*)out)[i] = o;
  }
}

// fused rms-norm + half-shift (reads x once; verified R5)
__global__ __launch_bounds__(256) void k_normshift(const float* __restrict__ x,
                                                   const float* __restrict__ g,
                                                   u16* __restrict__ xn2) {
  int t = blockIdx.x;
  int l = t & (LSEQ - 1);
  float2 v = ((const float2*)(x + (size_t)t * DIN))[threadIdx.x];
  float ss = v.x * v.x + v.y * v.y;
  for (int o = 32; o > 0; o >>= 1) ss += __shfl_down(ss, o, 64);
  __shared__ float p[4];
  if ((threadIdx.x & 63) == 0) p[threadIdx.x >> 6] = ss;
  __syncthreads();
  float s = p[0] + p[1] + p[2] + p[3];
  float norm = sqrtf(s * (1.0f / (float)DIN));
  float inv = g[0] / fmaxf(norm, 1e-5f);
  int d = threadIdx.x * 2;
  ushort2 ob; ob.x = f2bf(v.x * inv); ob.y = f2bf(v.y * inv);
  if (d >= 256) {
    *(ushort2*)(xn2 + (size_t)t * DIN + d) = ob;
  } else {
    if (l < LSEQ - 1) *(ushort2*)(xn2 + (size_t)(t + 1) * DIN + d) = ob;
    if (l == 0) { ushort2 z = {0, 0}; *(ushort2*)(xn2 + (size_t)t * DIN + d) = z; }
  }
}

// RoPE tables in double precision (match numpy)
__global__ __launch_bounds__(256) void k_rope_table(float* __restrict__ sin_t,
                                                    float* __restrict__ cos_t) {
  int idx = blockIdx.x * 256 + threadIdx.x;   // 1024*64
  int l = idx >> 6, j = idx & 63;
  double freq = pow(10000.0, (double)j / 64.0);
  float arg = (float)l * (float)freq;
  double a = (double)arg;
  sin_t[idx] = (float)sin(a);
  cos_t[idx] = (float)cos(a);
}

// base -> q,k with gamma/beta affine + RoPE
__global__ __launch_bounds__(256) void k_qkbuild(const u16* __restrict__ base,
                                                 const float* __restrict__ gamma,
                                                 const float* __restrict__ beta,
                                                 const float* __restrict__ sin_t,
                                                 const float* __restrict__ cos_t,
                                                 u16* __restrict__ q, u16* __restrict__ k) {
  int idx = blockIdx.x * 256 + threadIdx.x;   // NTOK*64
  int t = idx >> 6, j = idx & 63;
  int l = t & (LSEQ - 1);
  float b1 = bf2f(base[(size_t)t * SDIM + j]);
  float b2 = bf2f(base[(size_t)t * SDIM + j + 64]);
  float s = sin_t[l * 64 + j], c = cos_t[l * 64 + j];
  {
    float y1 = b1 * gamma[j] + beta[j];
    float y2 = b2 * gamma[64 + j] + beta[64 + j];
    q[(size_t)t * SDIM + j]      = f2bf(y1 * c - y2 * s);
    q[(size_t)t * SDIM + j + 64] = f2bf(y2 * c + y1 * s);
  }
  {
    float y1 = b1 * gamma[128 + j] + beta[128 + j];
    float y2 = b2 * gamma[192 + j] + beta[192 + j];
    k[(size_t)t * SDIM + j]      = f2bf(y1 * c - y2 * s);
    k[(size_t)t * SDIM + j + 64] = f2bf(y2 * c + y1 * s);
  }
}

// ============ 128x128 1-phase core (R4-verified) — used by qk only ============

__device__ __forceinline__ void stage128x32(const u16* g, int ld, u16* l, int tid) {
  int r = tid >> 2;
  int c = ((tid & 3) ^ ((tid >> 3) & 3)) * 8;
  const u16* g0 = g + (size_t)r * ld + c;
  const u16* g1 = g + (size_t)(r + 64) * ld + c;
  u16* l0 = l + tid * 8;
  u16* l1 = l + tid * 8 + 2048;
  __builtin_amdgcn_global_load_lds((AS1 unsigned int*)g0, (AS3 unsigned int*)l0, 16, 0, 0);
  __builtin_amdgcn_global_load_lds((AS1 unsigned int*)g1, (AS3 unsigned int*)l1, 16, 0, 0);
}

__device__ __forceinline__ void gemm_core(const u16* A, const u16* B, int K,
                                          int lda, int ldb,
                                          u16* sA, u16* sB, f32x4 acc[4][4]) {
  const int tid = threadIdx.x;
  const int lane = tid & 63;
  const int wid = tid >> 6;
  const int wr = wid >> 1, wc = wid & 1;
  const int fr = lane & 15, kg = lane >> 4;
  const int ks = (kg ^ ((fr >> 1) & 3)) * 8;
  const u16* sa_base = sA + (wr * 64 + fr) * 32 + ks;
  const u16* sb_base = sB + (wc * 64 + fr) * 32 + ks;
  for (int k0 = 0; k0 < K; k0 += 32) {
    stage128x32(A + k0, lda, sA, tid);
    stage128x32(B + k0, ldb, sB, tid);
    __syncthreads();
    bf16x8 a[4], b[4];
#pragma unroll
    for (int i = 0; i < 4; ++i) a[i] = *(const bf16x8*)(sa_base + i * 16 * 32);
#pragma unroll
    for (int i = 0; i < 4; ++i) b[i] = *(const bf16x8*)(sb_base + i * 16 * 32);
#pragma unroll
    for (int m = 0; m < 4; ++m)
#pragma unroll
      for (int n = 0; n < 4; ++n)
        acc[m][n] = __builtin_amdgcn_mfma_f32_16x16x32_bf16(a[m], b[n], acc[m][n], 0, 0, 0);
    __syncthreads();
  }
}

// ============ 256x256 8-wave pipelined core, per-slot quadrant schedule ============
// 512 thr = 8 waves (2M x 4N). BK=64, LDS 128KB (2 dbuf x (A 32K + B 32K)).
// Per K-tile, 4 slots. Slot s: MFMA M-quadrant q=s (16 mfma), pre-barrier issue of
// q=s+1 frag reads, barrier, then stage 2 gloads of tile t+2 INTO THE CURRENT buffer:
// A-quadrant s is dead after barrier_s (B fully register-resident after slot 0), so
// the same-buffer write is WAR-safe. Boundary: vmcnt(6) (t+2's 6 newest stay in
// flight — counted, never drains in steady state) + barrier.
// LDS swizzle: chunk ^= row&7 within each 128B row; gload source pre-swizzled
// (lane l: srow=l>>3, scol=((l&7)^(l>>3))*8), dest linear (HW: base+lane*16B).

#define GROW_A(s) (wr * 128 + (s) * 32 + wc * 8)
#define GROW_B(s) (wid * 32 + (s) * 8)

#define STG_PAIR(s, At2, Bt2, dA, dB)                                              \
  do {                                                                             \
    __builtin_amdgcn_global_load_lds(                                              \
        (AS1 unsigned int*)((At2) + (size_t)(GROW_A(s) + srow) * lda + scol),      \
        (AS3 unsigned int*)((dA) + GROW_A(s) * 64), 16, 0, 0);                     \
    __builtin_amdgcn_global_load_lds(                                              \
        (AS1 unsigned int*)((Bt2) + (size_t)(GROW_B(s) + srow) * ldb + scol),      \
        (AS3 unsigned int*)((dB) + GROW_B(s) * 64), 16, 0, 0);                     \
  } while (0)

#define RD_A(dst, cbuf, q)                                                         \
  do {                                                                             \
    _Pragma("unroll") for (int r_ = 0; r_ < 2; ++r_)                               \
    _Pragma("unroll") for (int h_ = 0; h_ < 2; ++h_)                               \
      dst[r_][h_] = *(const bf16x8*)((cbuf) + (wr * 128 + (q) * 32 + r_ * 16 + fr) * 64 + \
                                     (((h_ * 4 + kg) ^ fr7) * 8));                 \
  } while (0)

#define RD_B(cbuf)                                                                 \
  do {                                                                             \
    _Pragma("unroll") for (int n_ = 0; n_ < 4; ++n_)                               \
    _Pragma("unroll") for (int h_ = 0; h_ < 2; ++h_)                               \
      breg[n_][h_] = *(const bf16x8*)((cbuf) + (wc * 64 + n_ * 16 + fr) * 64 +     \
                                      (((h_ * 4 + kg) ^ fr7) * 8));                \
  } while (0)

#define MFMA16(s, areg)                                                            \
  do {                                                                             \
    __builtin_amdgcn_s_setprio(1);                                                 \
    _Pragma("unroll") for (int r_ = 0; r_ < 2; ++r_)                               \
    _Pragma("unroll") for (int n_ = 0; n_ < 4; ++n_)                               \
    _Pragma("unroll") for (int h_ = 0; h_ < 2; ++h_)                               \
      acc[(s) * 2 + r_][n_] = __builtin_amdgcn_mfma_f32_16x16x32_bf16(             \
          areg[r_][h_], breg[n_][h_], acc[(s) * 2 + r_][n_], 0, 0, 0);             \
    __builtin_amdgcn_s_setprio(0);                                                 \
  } while (0)

#define BAR_FENCE()                                                                \
  do { __builtin_amdgcn_s_barrier(); asm volatile("" ::: "memory"); } while (0)

__device__ __forceinline__ void gemm256p_core(const u16* __restrict__ A, int lda,
                                              const u16* __restrict__ B, int ldb,
                                              int K, u16* smem, f32x4 (&acc)[8][4]) {
  const int tid = threadIdx.x;
  const int lane = tid & 63, wid = tid >> 6;
  const int wr = wid >> 2, wc = wid & 3;
  const int fr = lane & 15, kg = lane >> 4, fr7 = fr & 7;
  const int srow = lane >> 3;
  const int scol = ((lane & 7) ^ srow) * 8;
  u16* cA = smem;
  u16* cB = smem + 16384;
  u16* nA = smem + 32768;
  u16* nB = smem + 49152;
  const int nt = K >> 6;

  // prologue: stage tile0 (8/wave) then tile1 (8/wave); wait tile0, keep tile1 in flight
#pragma unroll
  for (int s = 0; s < 4; ++s) STG_PAIR(s, A, B, cA, cB);
#pragma unroll
  for (int s = 0; s < 4; ++s) STG_PAIR(s, A + 64, B + 64, nA, nB);
  asm volatile("s_waitcnt vmcnt(8)" ::: "memory");
  BAR_FENCE();

  bf16x8 breg[4][2], ac[2][2], an[2][2];
  RD_B(cB);
  RD_A(ac, cA, 0);

  for (int t = 0; t < nt; ++t) {
    const bool st = (t + 2) < nt;
    const u16* At2 = A + (size_t)(t + 2) * 64;
    const u16* Bt2 = B + (size_t)(t + 2) * 64;
    // slot 0
    MFMA16(0, ac);
    RD_A(an, cA, 1);
    BAR_FENCE();
    if (st) STG_PAIR(0, At2, Bt2, cA, cB);
    // slot 1
    MFMA16(1, an);
    RD_A(ac, cA, 2);
    BAR_FENCE();
    if (st) STG_PAIR(1, At2, Bt2, cA, cB);
    // slot 2
    MFMA16(2, ac);
    RD_A(an, cA, 3);
    BAR_FENCE();
    if (st) STG_PAIR(2, At2, Bt2, cA, cB);
    // slot 3 + tile boundary
    MFMA16(3, an);
    if (st) asm volatile("s_waitcnt vmcnt(6)" ::: "memory");   // t+1 landed; t+2's 6 in flight
    else    asm volatile("s_waitcnt vmcnt(0)" ::: "memory");   // epilogue drain
    BAR_FENCE();
    if (st) STG_PAIR(3, At2, Bt2, cA, cB);
    { u16* tp = cA; cA = nA; nA = tp; tp = cB; cB = nB; nB = tp; }
    if (t + 1 < nt) { RD_B(cB); RD_A(ac, cA, 0); }
  }
}

// C/D layout: col = lane&15 (+n*16), row = (lane>>4)*4 + j (+frag*16)

// GEMM1: uv = silu(xn2 @ uv_w^T). Grid 1152 = 8 XCDs x 16 M-tiles x 9 N-tiles.
__global__ __launch_bounds__(512, 2) void k_gemm_uv(const u16* __restrict__ xn2,
                                                    const u16* __restrict__ wbf,
                                                    u16* __restrict__ u, u16* __restrict__ vt,
                                                    u16* __restrict__ base) {
  __shared__ __align__(16) u16 smem[65536];
  f32x4 acc[8][4] = {};
  int bid = blockIdx.x;
  int xcd = bid & 7;
  int off = bid >> 3;                 // 0..143
  int m0 = (xcd * 16 + off / 9) * 256;
  int n0 = (off % 9) * 256;
  gemm256p_core(xn2 + (size_t)m0 * DIN, DIN, wbf + (size_t)n0 * DIN, DIN, DIN, smem, acc);
  int lane = threadIdx.x & 63, wid = threadIdx.x >> 6;
  int wr = wid >> 2, wc = wid & 3;
  int cb = n0 + wc * 64 + (lane & 15);
  int rb = m0 + wr * 128 + (lane >> 4) * 4;
  if (n0 < EDIM) {                       // u columns
#pragma unroll
    for (int mm = 0; mm < 8; ++mm)
#pragma unroll
      for (int n = 0; n < 4; ++n) {
        int c = cb + n * 16;
#pragma unroll
        for (int j = 0; j < 4; ++j) {
          int r = rb + mm * 16 + j;
          u[(size_t)r * EDIM + c] = f2bf(fast_silu(acc[mm][n][j]));
        }
      }
  } else if (n0 < 2 * EDIM) {            // v columns -> transposed store
    int b = m0 >> 10;
    u16* vtb = vt + (size_t)b * (EDIM * LSEQ);
#pragma unroll
    for (int mm = 0; mm < 8; ++mm) {
      int l0 = (rb + mm * 16) & (LSEQ - 1);
#pragma unroll
      for (int n = 0; n < 4; ++n) {
        int e = cb + n * 16 - EDIM;
        ushort4 o;
        o.x = f2bf(fast_silu(acc[mm][n][0]));
        o.y = f2bf(fast_silu(acc[mm][n][1]));
        o.z = f2bf(fast_silu(acc[mm][n][2]));
        o.w = f2bf(fast_silu(acc[mm][n][3]));
        *(ushort4*)(vtb + (size_t)e * LSEQ + l0) = o;
      }
    }
  } else if (wc < 2) {                   // base columns (valid half-tile)
#pragma unroll
    for (int mm = 0; mm < 8; ++mm)
#pragma unroll
      for (int n = 0; n < 4; ++n) {
        int c = cb + n * 16 - 2 * EDIM;
#pragma unroll
        for (int j = 0; j < 4; ++j) {
          int r = rb + mm * 16 + j;
          base[(size_t)r * SDIM + c] = f2bf(fast_silu(acc[mm][n][j]));
        }
      }
  }
}

// GEMM2: scores = relu((q k^T + w)/sqrt(S))^2.  128^2 1-phase core.
// Grid 1024 = 8 XCDs x 2 batches x 64 tiles (16 batches per launch).
__global__ __launch_bounds__(256) void k_gemm_qk(const u16* __restrict__ q,
                                                 const u16* __restrict__ k,
                                                 const float* __restrict__ w,
                                                 u16* __restrict__ scores) {
  __shared__ __align__(16) u16 sA[4096];
  __shared__ __align__(16) u16 sB[4096];
  f32x4 acc[4][4] = {};
  int bid = blockIdx.x;
  int xcd = bid & 7;
  int off = bid >> 3;                    // 0..127
  int b = xcd * 2 + (off >> 6);          // chunk-local batch
  int t = off & 63;
  int m0 = (t >> 3) * 128, n0 = (t & 7) * 128;
  gemm_core(q + (size_t)(b * LSEQ + m0) * SDIM, k + (size_t)(b * LSEQ + n0) * SDIM,
            SDIM, SDIM, SDIM, sA, sB, acc);
  int lane = threadIdx.x & 63, wid = threadIdx.x >> 6;
  int wr = wid >> 1, wc = wid & 1;
  int cb = n0 + wc * 64 + (lane & 15);
  int rb = m0 + wr * 64 + (lane >> 4) * 4;
  const float inv_sqrt_s = 0.08838834764831845f;
  u16* sc_b = scores + (size_t)b * LSEQ * LSEQ;
#pragma unroll
  for (int m = 0; m < 4; ++m)
#pragma unroll
    for (int n = 0; n < 4; ++n) {
      int c = cb + n * 16;
#pragma unroll
      for (int j = 0; j < 4; ++j) {
        int r = rb + m * 16 + j;
        float val = (acc[m][n][j] + w[c - r + (LSEQ - 1)]) * inv_sqrt_s;
        val = fmaxf(val, 0.0f);
        sc_b[(size_t)r * LSEQ + c] = f2bf(val * val);
      }
    }
}

// GEMM3: u_io <- u_io .* (scores @ v).  256^2 pipelined core.
// Grid 256 = 8 XCDs x 2 batches x 16 tiles (16 batches per launch).
__global__ __launch_bounds__(512, 2) void k_gemm_pv(const u16* __restrict__ scores,
                                                    const u16* __restrict__ vt,
                                                    u16* u_io) {
  __shared__ __align__(16) u16 smem[65536];
  f32x4 acc[8][4] = {};
  int bid = blockIdx.x;
  int xcd = bid & 7;
  int off = bid >> 3;                    // 0..31
  int b = xcd * 2 + (off >> 4);          // chunk-local batch
  int t = off & 15;
  int m0 = (t >> 2) * 256, n0 = (t & 3) * 256;
  gemm256p_core(scores + (size_t)b * LSEQ * LSEQ + (size_t)m0 * LSEQ, LSEQ,
                vt + (size_t)b * LSEQ * EDIM + (size_t)n0 * LSEQ, LSEQ,
                LSEQ, smem, acc);
  int lane = threadIdx.x & 63, wid = threadIdx.x >> 6;
  int wr = wid >> 2, wc = wid & 3;
  int cb = n0 + wc * 64 + (lane & 15);
  int rb = m0 + wr * 128 + (lane >> 4) * 4;
#pragma unroll
  for (int mm = 0; mm < 8; ++mm)
#pragma unroll
    for (int n = 0; n < 4; ++n) {
      int c = cb + n * 16;
#pragma unroll
      for (int j = 0; j < 4; ++j) {
        int r = rb + mm * 16 + j;
        size_t idx = (size_t)(b * LSEQ + r) * EDIM + c;
        u_io[idx] = f2bf(acc[mm][n][j] * bf2f(u_io[idx]));
      }
    }
}

// GEMM4: out = x*res_scale + (attn @ o_w^T)*layer_scale.  256^2 pipelined core.
// Grid 256 = 8 XCDs x 16 M-tiles x 2 N-tiles.
__global__ __launch_bounds__(512, 2) void k_gemm_out(const u16* __restrict__ attn,
                                                     const u16* __restrict__ owbf,
                                                     const float* __restrict__ x,
                                                     const float* __restrict__ res_scale,
                                                     const float* __restrict__ layer_scale,
                                                     float* __restrict__ out) {
  __shared__ __align__(16) u16 smem[65536];
  f32x4 acc[8][4] = {};
  int bid = blockIdx.x;
  int xcd = bid & 7;
  int off = bid >> 3;                 // 0..31
  int m0 = (xcd * 16 + (off >> 1)) * 256;
  int n0 = (off & 1) * 256;
  gemm256p_core(attn + (size_t)m0 * EDIM, EDIM, owbf + (size_t)n0 * EDIM, EDIM,
                EDIM, smem, acc);
  int lane = threadIdx.x & 63, wid = threadIdx.x >> 6;
  int wr = wid >> 2, wc = wid & 3;
  int cb = n0 + wc * 64 + (lane & 15);
  int rb = m0 + wr * 128 + (lane >> 4) * 4;
#pragma unroll
  for (int mm = 0; mm < 8; ++mm)
#pragma unroll
    for (int n = 0; n < 4; ++n) {
      int c = cb + n * 16;
#pragma unroll
      for (int j = 0; j < 4; ++j) {
        int r = rb + mm * 16 + j;
        out[(size_t)r * DIN + c] =
            x[(size_t)r * DIN + c] * res_scale[c] + acc[mm][n][j] * layer_scale[c];
      }
    }
}

// ---------------- launch ----------------

extern "C" void kernel_launch(void* const* d_in, const int* in_sizes, int n_in,
                              void* d_out, int out_size, void* d_ws, size_t ws_size,
                              hipStream_t stream) {
  const float* x          = (const float*)d_in[0];
  const float* uv_w       = (const float*)d_in[1];
  const float* o_w        = (const float*)d_in[2];
  const float* gamma      = (const float*)d_in[3];
  const float* beta       = (const float*)d_in[4];
  const float* w          = (const float*)d_in[5];
  const float* g          = (const float*)d_in[6];
  const float* res_scale  = (const float*)d_in[7];
  const float* layer_scale= (const float*)d_in[8];
  float* out = (float*)d_out;

  char* ws = (char*)d_ws;
  // workspace layout (bytes), peak ~189 MB (< proven-good 197):
  u16* xn2    = (u16*)(ws + 0);            // 32 MB, dead after gemm_uv
  u16* q      = (u16*)(ws + 0);            // 8 MB (aliases dead xn2)
  u16* k      = (u16*)(ws + 8388608);      // 8 MB (aliases dead xn2)
  u16* scores = (u16*)(ws + 16777216);     // 32 MB (aliases dead xn2-upper + dead base)
  u16* base   = (u16*)(ws + 33554432);     // 8 MB, live gemm_uv -> qkbuild
  u16* u_io   = (u16*)(ws + 50331648);     // 64 MB: u, gated in place -> attn
  u16* vt     = (u16*)(ws + 117440512);    // 64 MB: v^T per batch
  u16* uvw_bf = (u16*)(ws + 184549376);    // 2.125 MB (+0.125 MB pad-read slack)
  u16* ow_bf  = (u16*)(ws + 186908672);    // 1 MB
  float* sin_t = (float*)(ws + 187957248); // 256 KB
  float* cos_t = (float*)(ws + 188219392); // 256 KB

  // prep
  k_f32_to_bf16<<<dim3((NUV * DIN / 4 + 255) / 256), 256, 0, stream>>>(uv_w, uvw_bf, NUV * DIN / 4);
  k_f32_to_bf16<<<dim3((DIN * EDIM / 4 + 255) / 256), 256, 0, stream>>>(o_w, ow_bf, DIN * EDIM / 4);
  k_rope_table<<<dim3(LSEQ * 64 / 256), 256, 0, stream>>>(sin_t, cos_t);
  k_normshift<<<dim3(NTOK), 256, 0, stream>>>(x, g, xn2);

  // uv projection + silu (256^2 per-slot-staged pipelined core)
  k_gemm_uv<<<dim3(1152), 512, 0, stream>>>(xn2, uvw_bf, u_io, vt, base);

  // q,k build (writes into dead xn2 region)
  k_qkbuild<<<dim3(NTOK * 64 / 256), 256, 0, stream>>>(base, gamma, beta, sin_t, cos_t, q, k);

  // scores + pv, chunked by 16 batches
  for (int ch = 0; ch < NB / CHUNK; ++ch) {
    size_t tok0 = (size_t)ch * CHUNK * LSEQ;
    k_gemm_qk<<<dim3(1024), 256, 0, stream>>>(q + tok0 * SDIM, k + tok0 * SDIM, w, scores);
    k_gemm_pv<<<dim3(256), 512, 0, stream>>>(scores, vt + tok0 * EDIM, u_io + tok0 * EDIM);
  }

  // final projection + residual (256^2 pipelined core)
  k_gemm_out<<<dim3(256), 512, 0, stream>>>(u_io, ow_bf, x, res_scale, layer_scale, out);
}